// Round 9
// baseline (139.567 us; speedup 1.0000x reference)
//
#include <hip/hip_runtime.h>

#define IN_DIM   256
#define OUT_DIM  64
#define NEG_SLOPE 0.01f
#define KPAD (IN_DIM + 8)     // bf16; +16B pad -> conflict-light ds accesses
#define MAXBUCK 2048
#define CAP     1024          // slots/bucket (mean 512, 22 sigma < 1024)
#define EPB     8192          // edges per multisplit block (32 regs of staging)

typedef __attribute__((ext_vector_type(8))) short short8;   // 8 bf16
typedef __attribute__((ext_vector_type(4))) float f32x4;
typedef unsigned short ushort_t;

__device__ inline unsigned f2bf_u(float f) {
    unsigned u = __float_as_uint(f);
    return (u + 0x7FFF + ((u >> 16) & 1)) >> 16;            // RNE, low 16 bits
}
__device__ inline short f2bf(float f) { return (short)f2bf_u(f); }
__device__ inline float bf2f(unsigned u16) { return __uint_as_float(u16 << 16); }

// ---------------------------------------------------------------------------
// P0 (8 blocks): zero bucket counters + W (256x64 fp32 [k][n]) -> Wt
// (64x256 bf16 [n][k]). Merged (R6 A/B: separate memset dispatch costs ~3us).
// ---------------------------------------------------------------------------
__global__ __launch_bounds__(256)
void prep_kernel(const float* __restrict__ W, short* __restrict__ Wt,
                 int* __restrict__ cnt, int nbuck)
{
    const int g = blockIdx.x * 256 + threadIdx.x;
    for (int i = g; i < nbuck; i += 8 * 256) cnt[i] = 0;
    for (int i = g; i < IN_DIM * OUT_DIM; i += 8 * 256) {
        const int k = i & (IN_DIM - 1);
        const int n = i >> 8;                      // IN_DIM == 256
        Wt[i] = f2bf(W[(size_t)k * OUT_DIM + n]);
    }
}

// ---------------------------------------------------------------------------
// K1 (fused): blocks [0, ms_blocks) do the bucketed multisplit; the rest do
// the MFMA gemm (z = h@W + fused s_l/s_r). Data-independent halves overlap.
// ---------------------------------------------------------------------------
__global__ __launch_bounds__(256, 4)
void fused_kernel(const float* __restrict__ h, const short* __restrict__ Wt,
                  const float* __restrict__ a_attn,
                  ushort_t* __restrict__ z_bf, float* __restrict__ s_l,
                  float* __restrict__ s_r,
                  const int* __restrict__ esrc, const int* __restrict__ edst,
                  int* __restrict__ cnt, unsigned* __restrict__ perm,
                  int n_nodes, int n_edges, int nbuck, int ms_blocks)
{
    __shared__ union {
        short As[64 * KPAD];                                // 33792 B (gemm)
        struct { int hist[MAXBUCK]; int cur[MAXBUCK]; } m;  // 16384 B (multisplit)
    } sm;

    const int tid = threadIdx.x;

    if ((int)blockIdx.x < ms_blocks) {
        // ---------------- multisplit ----------------
        for (int i = tid; i < nbuck; i += 256) sm.m.hist[i] = 0;
        __syncthreads();
        const int base = blockIdx.x * EPB;
        unsigned pw[EPB / 256];
#pragma unroll
        for (int j = 0; j < EPB / 256; ++j) {
            const int i = base + j * 256 + tid;
            unsigned w = 0xFFFFFFFFu;
            if (i < n_edges) {
                const int d = edst[i];
                w = ((unsigned)d << 16) | (unsigned)esrc[i];
                atomicAdd(&sm.m.hist[d >> 5], 1);
            }
            pw[j] = w;
        }
        __syncthreads();
        for (int i = tid; i < nbuck; i += 256) {
            const int hv = sm.m.hist[i];
            if (hv) sm.m.cur[i] = i * CAP + atomicAdd(&cnt[i], hv);
        }
        __syncthreads();
#pragma unroll
        for (int j = 0; j < EPB / 256; ++j) {
            const unsigned w = pw[j];
            if (w != 0xFFFFFFFFu) {
                const int bk = (int)(w >> 21);
                const int pos = atomicAdd(&sm.m.cur[bk], 1);
                if (pos < (bk + 1) * CAP) perm[pos] = w;   // overflow guard
            }
        }
        return;
    }

    // ---------------- gemm: z = h @ W, fused s_l/s_r ----------------
    const int wave = tid >> 6;
    const int lane = tid & 63;
    const int nbase = ((int)blockIdx.x - ms_blocks) * 64;

    // stage A: one float4 load -> packed uint2 -> single ds_write_b64
    for (int i = tid; i < 64 * (IN_DIM / 4); i += 256) {
        const int m  = i >> 6;
        const int k4 = i & 63;
        int node = nbase + m;
        if (node >= n_nodes) node = n_nodes - 1;
        const float4 h4 = *(const float4*)&h[(size_t)node * IN_DIM + k4 * 4];
        uint2 p;
        p.x = f2bf_u(h4.x) | (f2bf_u(h4.y) << 16);
        p.y = f2bf_u(h4.z) | (f2bf_u(h4.w) << 16);
        *(uint2*)&sm.As[m * KPAD + k4 * 4] = p;
    }
    __syncthreads();

    f32x4 acc[4];
#pragma unroll
    for (int t = 0; t < 4; ++t) acc[t] = (f32x4){0.f, 0.f, 0.f, 0.f};

    const int col0 = lane & 15;
    const int quad = lane >> 4;
    const int mrow = wave * 16 + col0;
    const int kq   = quad * 8;

#pragma unroll
    for (int ks = 0; ks < IN_DIM / 32; ++ks) {
        const int kb = ks * 32 + kq;
        const short8 a = *(const short8*)&sm.As[mrow * KPAD + kb];
#pragma unroll
        for (int t = 0; t < 4; ++t) {
            const short8 b = *(const short8*)&Wt[(t * 16 + col0) * IN_DIM + kb];
            acc[t] = __builtin_amdgcn_mfma_f32_16x16x32_bf16(a, b, acc[t], 0, 0, 0);
        }
    }

    float al[4], ar[4];
#pragma unroll
    for (int t = 0; t < 4; ++t) {
        al[t] = a_attn[t * 16 + col0];
        ar[t] = a_attn[OUT_DIM + t * 16 + col0];
    }
#pragma unroll
    for (int r = 0; r < 4; ++r) {
        const int m = nbase + wave * 16 + quad * 4 + r;
        const bool live = m < n_nodes;
        float sl = 0.f, sr = 0.f;
#pragma unroll
        for (int t = 0; t < 4; ++t) {
            const float v = acc[t][r];
            if (live) z_bf[(size_t)m * OUT_DIM + t * 16 + col0] = (ushort_t)f2bf(v);
            sl += v * al[t];
            sr += v * ar[t];
        }
#pragma unroll
        for (int off = 1; off < 16; off <<= 1) {
            sl += __shfl_xor(sl, off, 16);
            sr += __shfl_xor(sr, off, 16);
        }
        if (live && col0 == 0) { s_l[m] = sl; s_r[m] = sr; }
    }
}

// ---------------------------------------------------------------------------
// K2: fused per-bucket CSR + softmax gather (CSR built in LDS, register
// accumulation, x8-unrolled independent gathers for MLP).
// One block (512 thr) per bucket; quarter-wave (16 lanes) per dst.
// ---------------------------------------------------------------------------
__global__ __launch_bounds__(512)
void gather_kernel(const unsigned* __restrict__ perm, const int* __restrict__ cnt,
                   const float* __restrict__ s_l, const float* __restrict__ s_r,
                   const ushort_t* __restrict__ z_bf, float* __restrict__ out,
                   int n_nodes)
{
    __shared__ unsigned eds[CAP];
    __shared__ ushort_t srcs[CAP];
    __shared__ int hist[32], starts[33], cur[32];

    const int tid = threadIdx.x;
    const int b   = blockIdx.x;
    int nE = cnt[b];
    if (nE > CAP) nE = CAP;

    if (tid < 32) hist[tid] = 0;
    __syncthreads();

    for (int i = tid; i < nE; i += 512) {
        const unsigned p = perm[(size_t)b * CAP + i];
        eds[i] = p;
        atomicAdd(&hist[(p >> 16) & 31], 1);
    }
    __syncthreads();

    if (tid < 32) {
        const int v = hist[tid];
        int inc = v;
#pragma unroll
        for (int off = 1; off < 32; off <<= 1) {
            const int u = __shfl_up(inc, off, 32);
            if (tid >= off) inc += u;
        }
        starts[tid + 1] = inc;
        cur[tid] = inc - v;
        if (tid == 0) starts[0] = 0;
    }
    __syncthreads();

    for (int i = tid; i < nE; i += 512) {
        const unsigned p = eds[i];
        const int pos = atomicAdd(&cur[(p >> 16) & 31], 1);
        srcs[pos] = (ushort_t)(p & 0xFFFFu);
    }
    __syncthreads();

    const int ld = tid >> 4;        // 0..31: dst within bucket
    const int c  = tid & 15;        // column quad
    const int d  = b * 32 + ld;
    if (d >= n_nodes) return;

    int k = starts[ld];
    const int ke = starts[ld + 1];
    const float srd = s_r[d];

    float a0 = 0.f, a1 = 0.f, a2 = 0.f, a3 = 0.f, den = 0.f;

    for (; k + 8 <= ke; k += 8) {
        int   s[8];
        float l[8];
        uint2 q[8];
#pragma unroll
        for (int j = 0; j < 8; ++j) s[j] = srcs[k + j];
#pragma unroll
        for (int j = 0; j < 8; ++j) {
            l[j] = s_l[s[j]];
            q[j] = *(const uint2*)&z_bf[(size_t)s[j] * OUT_DIM + c * 4];
        }
#pragma unroll
        for (int j = 0; j < 8; ++j) {
            float e = l[j] + srd;
            e = e > 0.f ? e : NEG_SLOPE * e;
            const float x = __expf(e);
            den += x;
            a0 += x * bf2f(q[j].x & 0xFFFFu);
            a1 += x * bf2f(q[j].x >> 16);
            a2 += x * bf2f(q[j].y & 0xFFFFu);
            a3 += x * bf2f(q[j].y >> 16);
        }
    }
    for (; k + 4 <= ke; k += 4) {
        int   s[4];
        float l[4];
        uint2 q[4];
#pragma unroll
        for (int j = 0; j < 4; ++j) s[j] = srcs[k + j];
#pragma unroll
        for (int j = 0; j < 4; ++j) {
            l[j] = s_l[s[j]];
            q[j] = *(const uint2*)&z_bf[(size_t)s[j] * OUT_DIM + c * 4];
        }
#pragma unroll
        for (int j = 0; j < 4; ++j) {
            float e = l[j] + srd;
            e = e > 0.f ? e : NEG_SLOPE * e;
            const float x = __expf(e);
            den += x;
            a0 += x * bf2f(q[j].x & 0xFFFFu);
            a1 += x * bf2f(q[j].x >> 16);
            a2 += x * bf2f(q[j].y & 0xFFFFu);
            a3 += x * bf2f(q[j].y >> 16);
        }
    }
    for (; k < ke; ++k) {
        const int s0 = srcs[k];
        float e = s_l[s0] + srd;
        e = e > 0.f ? e : NEG_SLOPE * e;
        const float x = __expf(e);
        const uint2 q0 = *(const uint2*)&z_bf[(size_t)s0 * OUT_DIM + c * 4];
        den += x;
        a0 += x * bf2f(q0.x & 0xFFFFu);
        a1 += x * bf2f(q0.x >> 16);
        a2 += x * bf2f(q0.y & 0xFFFFu);
        a3 += x * bf2f(q0.y >> 16);
    }

    const float inv = den > 0.f ? 1.f / den : 0.f;
    float4 o;
    o.x = a0 * inv; o.y = a1 * inv; o.z = a2 * inv; o.w = a3 * inv;
    *(float4*)&out[(size_t)d * OUT_DIM + c * 4] = o;
}

extern "C" void kernel_launch(void* const* d_in, const int* in_sizes, int n_in,
                              void* d_out, int out_size, void* d_ws, size_t ws_size,
                              hipStream_t stream)
{
    const float* h        = (const float*)d_in[0];
    const int*   edge_src = (const int*)  d_in[1];
    const int*   edge_dst = (const int*)  d_in[2];
    const float* W        = (const float*)d_in[3];
    const float* a_attn   = (const float*)d_in[4];
    float*       out      = (float*)d_out;

    const int n_nodes = in_sizes[0] / IN_DIM;   // 50000
    const int n_edges = in_sizes[1];            // 800000
    const int nbuck   = (n_nodes + 31) >> 5;    // 1563

    // ---- workspace layout (16B-aligned regions) ----------------------------
    char* wsb = (char*)d_ws;
    short*    Wt   = (short*)wsb;
    size_t off = (size_t)IN_DIM * OUT_DIM * sizeof(short);          // 32 KB
    ushort_t* z_bf = (ushort_t*)(wsb + off);
    off += (size_t)n_nodes * OUT_DIM * sizeof(ushort_t);            // 6.4 MB
    float*    s_l  = (float*)(wsb + off);  off += (size_t)n_nodes * 4;
    float*    s_r  = (float*)(wsb + off);  off += (size_t)n_nodes * 4;
    int*      cnt  = (int*)(wsb + off);    off += ((size_t)nbuck * 4 + 15) & ~(size_t)15;
    unsigned* perm = (unsigned*)(wsb + off);                        // nbuck*CAP*4 = 6.4 MB

    const int ms_blocks   = (n_edges + EPB - 1) / EPB;   // 98
    const int gemm_blocks = (n_nodes + 63) / 64;         // 782

    prep_kernel<<<8, 256, 0, stream>>>(W, Wt, cnt, nbuck);
    fused_kernel<<<ms_blocks + gemm_blocks, 256, 0, stream>>>(
        h, Wt, a_attn, z_bf, s_l, s_r, edge_src, edge_dst, cnt, perm,
        n_nodes, n_edges, nbuck, ms_blocks);
    gather_kernel<<<nbuck, 512, 0, stream>>>(
        perm, cnt, s_l, s_r, z_bf, out, n_nodes);
}

// Round 10
// 138.243 us; speedup vs baseline: 1.0096x; 1.0096x over previous
//
#include <hip/hip_runtime.h>

#define IN_DIM   256
#define OUT_DIM  64
#define NEG_SLOPE 0.01f
#define KPAD (IN_DIM + 8)     // bf16; +16B pad -> conflict-light ds accesses
#define MAXBUCK 2048
#define CAP     1024          // slots/bucket (mean 512, 22 sigma < 1024)
#define EPB     4096          // edges per multisplit block (R6-proven; 8192 regressed)

typedef __attribute__((ext_vector_type(8))) short short8;   // 8 bf16
typedef __attribute__((ext_vector_type(4))) float f32x4;
typedef unsigned short ushort_t;

__device__ inline unsigned f2bf_u(float f) {
    unsigned u = __float_as_uint(f);
    return (u + 0x7FFF + ((u >> 16) & 1)) >> 16;            // RNE, low 16 bits
}
__device__ inline short f2bf(float f) { return (short)f2bf_u(f); }
__device__ inline float bf2f(unsigned u16) { return __uint_as_float(u16 << 16); }

// ---------------------------------------------------------------------------
// P0 (8 blocks): zero bucket counters + W (256x64 fp32 [k][n]) -> Wt
// (64x256 bf16 [n][k]). Merged (R6 A/B: separate memset dispatch costs ~3us).
// ---------------------------------------------------------------------------
__global__ __launch_bounds__(256)
void prep_kernel(const float* __restrict__ W, short* __restrict__ Wt,
                 int* __restrict__ cnt, int nbuck)
{
    const int g = blockIdx.x * 256 + threadIdx.x;
    for (int i = g; i < nbuck; i += 8 * 256) cnt[i] = 0;
    for (int i = g; i < IN_DIM * OUT_DIM; i += 8 * 256) {
        const int k = i & (IN_DIM - 1);
        const int n = i >> 8;                      // IN_DIM == 256
        Wt[i] = f2bf(W[(size_t)k * OUT_DIM + n]);
    }
}

// ---------------------------------------------------------------------------
// K1 (fused): blocks [0, ms_blocks) do the bucketed multisplit; the rest do
// the MFMA gemm (z = h@W + fused s_l/s_r). Data-independent halves overlap.
// ---------------------------------------------------------------------------
__global__ __launch_bounds__(256, 4)
void fused_kernel(const float* __restrict__ h, const short* __restrict__ Wt,
                  const float* __restrict__ a_attn,
                  ushort_t* __restrict__ z_bf, float* __restrict__ s_l,
                  float* __restrict__ s_r,
                  const int* __restrict__ esrc, const int* __restrict__ edst,
                  int* __restrict__ cnt, unsigned* __restrict__ perm,
                  int n_nodes, int n_edges, int nbuck, int ms_blocks)
{
    __shared__ union {
        short As[64 * KPAD];                                // 33792 B (gemm)
        struct { int hist[MAXBUCK]; int cur[MAXBUCK]; } m;  // 16384 B (multisplit)
    } sm;

    const int tid = threadIdx.x;

    if ((int)blockIdx.x < ms_blocks) {
        // ---------------- multisplit ----------------
        for (int i = tid; i < nbuck; i += 256) sm.m.hist[i] = 0;
        __syncthreads();
        const int base = blockIdx.x * EPB;
        unsigned pw[EPB / 256];
#pragma unroll
        for (int j = 0; j < EPB / 256; ++j) {
            const int i = base + j * 256 + tid;
            unsigned w = 0xFFFFFFFFu;
            if (i < n_edges) {
                const int d = edst[i];
                w = ((unsigned)d << 16) | (unsigned)esrc[i];
                atomicAdd(&sm.m.hist[d >> 5], 1);
            }
            pw[j] = w;
        }
        __syncthreads();
        for (int i = tid; i < nbuck; i += 256) {
            const int hv = sm.m.hist[i];
            if (hv) sm.m.cur[i] = i * CAP + atomicAdd(&cnt[i], hv);
        }
        __syncthreads();
#pragma unroll
        for (int j = 0; j < EPB / 256; ++j) {
            const unsigned w = pw[j];
            if (w != 0xFFFFFFFFu) {
                const int bk = (int)(w >> 21);
                const int pos = atomicAdd(&sm.m.cur[bk], 1);
                if (pos < (bk + 1) * CAP) perm[pos] = w;   // overflow guard
            }
        }
        return;
    }

    // ---------------- gemm: z = h @ W, fused s_l/s_r ----------------
    const int wave = tid >> 6;
    const int lane = tid & 63;
    const int nbase = ((int)blockIdx.x - ms_blocks) * 64;

    // stage A: one float4 load -> packed uint2 -> single ds_write_b64
    for (int i = tid; i < 64 * (IN_DIM / 4); i += 256) {
        const int m  = i >> 6;
        const int k4 = i & 63;
        int node = nbase + m;
        if (node >= n_nodes) node = n_nodes - 1;
        const float4 h4 = *(const float4*)&h[(size_t)node * IN_DIM + k4 * 4];
        uint2 p;
        p.x = f2bf_u(h4.x) | (f2bf_u(h4.y) << 16);
        p.y = f2bf_u(h4.z) | (f2bf_u(h4.w) << 16);
        *(uint2*)&sm.As[m * KPAD + k4 * 4] = p;
    }
    __syncthreads();

    f32x4 acc[4];
#pragma unroll
    for (int t = 0; t < 4; ++t) acc[t] = (f32x4){0.f, 0.f, 0.f, 0.f};

    const int col0 = lane & 15;
    const int quad = lane >> 4;
    const int mrow = wave * 16 + col0;
    const int kq   = quad * 8;

#pragma unroll
    for (int ks = 0; ks < IN_DIM / 32; ++ks) {
        const int kb = ks * 32 + kq;
        const short8 a = *(const short8*)&sm.As[mrow * KPAD + kb];
#pragma unroll
        for (int t = 0; t < 4; ++t) {
            const short8 b = *(const short8*)&Wt[(t * 16 + col0) * IN_DIM + kb];
            acc[t] = __builtin_amdgcn_mfma_f32_16x16x32_bf16(a, b, acc[t], 0, 0, 0);
        }
    }

    float al[4], ar[4];
#pragma unroll
    for (int t = 0; t < 4; ++t) {
        al[t] = a_attn[t * 16 + col0];
        ar[t] = a_attn[OUT_DIM + t * 16 + col0];
    }
#pragma unroll
    for (int r = 0; r < 4; ++r) {
        const int m = nbase + wave * 16 + quad * 4 + r;
        const bool live = m < n_nodes;
        float sl = 0.f, sr = 0.f;
#pragma unroll
        for (int t = 0; t < 4; ++t) {
            const float v = acc[t][r];
            if (live) z_bf[(size_t)m * OUT_DIM + t * 16 + col0] = (ushort_t)f2bf(v);
            sl += v * al[t];
            sr += v * ar[t];
        }
#pragma unroll
        for (int off = 1; off < 16; off <<= 1) {
            sl += __shfl_xor(sl, off, 16);
            sr += __shfl_xor(sr, off, 16);
        }
        if (live && col0 == 0) { s_l[m] = sl; s_r[m] = sr; }
    }
}

// ---------------------------------------------------------------------------
// K2: fused per-bucket CSR + softmax gather. CSR built in LDS, register
// accumulation, x8-unrolled independent gathers (R6 core). New: TWO 8-lane
// groups per dst, each walking half the segment (halves the max-degree
// serial tail); lane owns 8 cols via 16B uint4 z loads. Partials merged
// once via a non-atomic LDS tile in the epilogue.
// ---------------------------------------------------------------------------
__global__ __launch_bounds__(512)
void gather_kernel(const unsigned* __restrict__ perm, const int* __restrict__ cnt,
                   const float* __restrict__ s_l, const float* __restrict__ s_r,
                   const ushort_t* __restrict__ z_bf, float* __restrict__ out,
                   int n_nodes)
{
    __shared__ unsigned eds[CAP];                 // 4 KB
    __shared__ ushort_t srcs[CAP];                // 2 KB
    __shared__ float accH[2][32][OUT_DIM];        // 16 KB
    __shared__ float denH[2][32];
    __shared__ int hist[32], starts[33], cur[32];

    const int tid = threadIdx.x;
    const int b   = blockIdx.x;
    int nE = cnt[b];
    if (nE > CAP) nE = CAP;

    if (tid < 32) hist[tid] = 0;
    __syncthreads();

    for (int i = tid; i < nE; i += 512) {
        const unsigned p = perm[(size_t)b * CAP + i];
        eds[i] = p;
        atomicAdd(&hist[(p >> 16) & 31], 1);
    }
    __syncthreads();

    if (tid < 32) {
        const int v = hist[tid];
        int inc = v;
#pragma unroll
        for (int off = 1; off < 32; off <<= 1) {
            const int u = __shfl_up(inc, off, 32);
            if (tid >= off) inc += u;
        }
        starts[tid + 1] = inc;
        cur[tid] = inc - v;
        if (tid == 0) starts[0] = 0;
    }
    __syncthreads();

    for (int i = tid; i < nE; i += 512) {
        const unsigned p = eds[i];
        const int pos = atomicAdd(&cur[(p >> 16) & 31], 1);
        srcs[pos] = (ushort_t)(p & 0xFFFFu);
    }
    __syncthreads();

    const int grp  = tid >> 3;       // 0..63
    const int ld   = grp >> 1;       // dst within bucket
    const int half = grp & 1;        // which half of the segment
    const int c2   = tid & 7;        // column octet: cols 8*c2 .. 8*c2+7
    const int d    = b * 32 + ld;

    const int begin = starts[ld];
    const int end   = starts[ld + 1];
    const int mid   = begin + ((end - begin + 1) >> 1);
    int k  = half ? mid : begin;
    const int ke = half ? end : mid;
    const float srd = (d < n_nodes) ? s_r[d] : 0.f;

    float a[8];
#pragma unroll
    for (int t = 0; t < 8; ++t) a[t] = 0.f;
    float den = 0.f;

    for (; k + 8 <= ke; k += 8) {
        int   s[8];
        float l[8];
        uint4 q[8];
#pragma unroll
        for (int j = 0; j < 8; ++j) s[j] = srcs[k + j];
#pragma unroll
        for (int j = 0; j < 8; ++j) {
            l[j] = s_l[s[j]];
            q[j] = *(const uint4*)&z_bf[(size_t)s[j] * OUT_DIM + c2 * 8];
        }
#pragma unroll
        for (int j = 0; j < 8; ++j) {
            float e = l[j] + srd;
            e = e > 0.f ? e : NEG_SLOPE * e;
            const float x = __expf(e);
            den += x;
            a[0] += x * bf2f(q[j].x & 0xFFFFu);
            a[1] += x * bf2f(q[j].x >> 16);
            a[2] += x * bf2f(q[j].y & 0xFFFFu);
            a[3] += x * bf2f(q[j].y >> 16);
            a[4] += x * bf2f(q[j].z & 0xFFFFu);
            a[5] += x * bf2f(q[j].z >> 16);
            a[6] += x * bf2f(q[j].w & 0xFFFFu);
            a[7] += x * bf2f(q[j].w >> 16);
        }
    }
    for (; k < ke; ++k) {
        const int s0 = srcs[k];
        float e = s_l[s0] + srd;
        e = e > 0.f ? e : NEG_SLOPE * e;
        const float x = __expf(e);
        const uint4 q0 = *(const uint4*)&z_bf[(size_t)s0 * OUT_DIM + c2 * 8];
        den += x;
        a[0] += x * bf2f(q0.x & 0xFFFFu);
        a[1] += x * bf2f(q0.x >> 16);
        a[2] += x * bf2f(q0.y & 0xFFFFu);
        a[3] += x * bf2f(q0.y >> 16);
        a[4] += x * bf2f(q0.z & 0xFFFFu);
        a[5] += x * bf2f(q0.z >> 16);
        a[6] += x * bf2f(q0.w & 0xFFFFu);
        a[7] += x * bf2f(q0.w >> 16);
    }

    // write partials (non-atomic) and merge in the epilogue
#pragma unroll
    for (int t = 0; t < 8; ++t) accH[half][ld][c2 * 8 + t] = a[t];
    if (c2 == 0) denH[half][ld] = den;
    __syncthreads();

    for (int i = tid; i < 32 * 16; i += 512) {
        const int l2 = i >> 4;
        const int cq = i & 15;
        const int dd = b * 32 + l2;
        if (dd < n_nodes) {
            const float dn = denH[0][l2] + denH[1][l2];
            const float inv = dn > 0.f ? 1.f / dn : 0.f;
            const float* r0 = &accH[0][l2][cq * 4];
            const float* r1 = &accH[1][l2][cq * 4];
            float4 o;
            o.x = (r0[0] + r1[0]) * inv;
            o.y = (r0[1] + r1[1]) * inv;
            o.z = (r0[2] + r1[2]) * inv;
            o.w = (r0[3] + r1[3]) * inv;
            *(float4*)&out[(size_t)dd * OUT_DIM + cq * 4] = o;
        }
    }
}

extern "C" void kernel_launch(void* const* d_in, const int* in_sizes, int n_in,
                              void* d_out, int out_size, void* d_ws, size_t ws_size,
                              hipStream_t stream)
{
    const float* h        = (const float*)d_in[0];
    const int*   edge_src = (const int*)  d_in[1];
    const int*   edge_dst = (const int*)  d_in[2];
    const float* W        = (const float*)d_in[3];
    const float* a_attn   = (const float*)d_in[4];
    float*       out      = (float*)d_out;

    const int n_nodes = in_sizes[0] / IN_DIM;   // 50000
    const int n_edges = in_sizes[1];            // 800000
    const int nbuck   = (n_nodes + 31) >> 5;    // 1563

    // ---- workspace layout (16B-aligned regions) ----------------------------
    char* wsb = (char*)d_ws;
    short*    Wt   = (short*)wsb;
    size_t off = (size_t)IN_DIM * OUT_DIM * sizeof(short);          // 32 KB
    ushort_t* z_bf = (ushort_t*)(wsb + off);
    off += (size_t)n_nodes * OUT_DIM * sizeof(ushort_t);            // 6.4 MB
    float*    s_l  = (float*)(wsb + off);  off += (size_t)n_nodes * 4;
    float*    s_r  = (float*)(wsb + off);  off += (size_t)n_nodes * 4;
    int*      cnt  = (int*)(wsb + off);    off += ((size_t)nbuck * 4 + 15) & ~(size_t)15;
    unsigned* perm = (unsigned*)(wsb + off);                        // nbuck*CAP*4 = 6.4 MB

    const int ms_blocks   = (n_edges + EPB - 1) / EPB;   // 196
    const int gemm_blocks = (n_nodes + 63) / 64;         // 782

    prep_kernel<<<8, 256, 0, stream>>>(W, Wt, cnt, nbuck);
    fused_kernel<<<ms_blocks + gemm_blocks, 256, 0, stream>>>(
        h, Wt, a_attn, z_bf, s_l, s_r, edge_src, edge_dst, cnt, perm,
        n_nodes, n_edges, nbuck, ms_blocks);
    gather_kernel<<<nbuck, 512, 0, stream>>>(
        perm, cnt, s_l, s_r, z_bf, out, n_nodes);
}

// Round 11
// 134.211 us; speedup vs baseline: 1.0399x; 1.0300x over previous
//
#include <hip/hip_runtime.h>

#define IN_DIM   256
#define OUT_DIM  64
#define NEG_SLOPE 0.01f
#define KPAD (IN_DIM + 8)     // bf16; +16B pad -> conflict-light ds accesses
#define MAXBUCK 2048
#define CAP     1024          // slots/bucket (mean 512, 22 sigma < 1024)
#define EPB     4096          // edges per multisplit block (proven best; 8192 regressed)

typedef __attribute__((ext_vector_type(8))) short short8;   // 8 bf16
typedef __attribute__((ext_vector_type(4))) float f32x4;
typedef unsigned short ushort_t;

__device__ inline unsigned f2bf_u(float f) {
    unsigned u = __float_as_uint(f);
    return (u + 0x7FFF + ((u >> 16) & 1)) >> 16;            // RNE, low 16 bits
}
__device__ inline short f2bf(float f) { return (short)f2bf_u(f); }
__device__ inline float bf2f(unsigned u16) { return __uint_as_float(u16 << 16); }

// ---------------------------------------------------------------------------
// P0 (8 blocks): zero bucket counters + W (256x64 fp32 [k][n]) -> Wt
// (64x256 bf16 [n][k]). Merged cnt-zero (A/B: separate memset costs ~3us).
// ---------------------------------------------------------------------------
__global__ __launch_bounds__(256)
void prep_kernel(const float* __restrict__ W, short* __restrict__ Wt,
                 int* __restrict__ cnt, int nbuck)
{
    const int g = blockIdx.x * 256 + threadIdx.x;
    for (int i = g; i < nbuck; i += 8 * 256) cnt[i] = 0;
    for (int i = g; i < IN_DIM * OUT_DIM; i += 8 * 256) {
        const int k = i & (IN_DIM - 1);
        const int n = i >> 8;                      // IN_DIM == 256
        Wt[i] = f2bf(W[(size_t)k * OUT_DIM + n]);
    }
}

// ---------------------------------------------------------------------------
// K1 (fused): blocks [0, ms_blocks) do the bucketed multisplit; the rest do
// the MFMA gemm (z = h@W + fused s_l/s_r). Data-independent halves overlap.
// ---------------------------------------------------------------------------
__global__ __launch_bounds__(256, 4)
void fused_kernel(const float* __restrict__ h, const short* __restrict__ Wt,
                  const float* __restrict__ a_attn,
                  ushort_t* __restrict__ z_bf, float* __restrict__ s_l,
                  float* __restrict__ s_r,
                  const int* __restrict__ esrc, const int* __restrict__ edst,
                  int* __restrict__ cnt, unsigned* __restrict__ perm,
                  int n_nodes, int n_edges, int nbuck, int ms_blocks)
{
    __shared__ union {
        short As[64 * KPAD];                                // 33792 B (gemm)
        struct { int hist[MAXBUCK]; int cur[MAXBUCK]; } m;  // 16384 B (multisplit)
    } sm;

    const int tid = threadIdx.x;

    if ((int)blockIdx.x < ms_blocks) {
        // ---------------- multisplit ----------------
        for (int i = tid; i < nbuck; i += 256) sm.m.hist[i] = 0;
        __syncthreads();
        const int base = blockIdx.x * EPB;
        unsigned pw[EPB / 256];
#pragma unroll
        for (int j = 0; j < EPB / 256; ++j) {
            const int i = base + j * 256 + tid;
            unsigned w = 0xFFFFFFFFu;
            if (i < n_edges) {
                const int d = edst[i];
                w = ((unsigned)d << 16) | (unsigned)esrc[i];
                atomicAdd(&sm.m.hist[d >> 5], 1);
            }
            pw[j] = w;
        }
        __syncthreads();
        for (int i = tid; i < nbuck; i += 256) {
            const int hv = sm.m.hist[i];
            if (hv) sm.m.cur[i] = i * CAP + atomicAdd(&cnt[i], hv);
        }
        __syncthreads();
#pragma unroll
        for (int j = 0; j < EPB / 256; ++j) {
            const unsigned w = pw[j];
            if (w != 0xFFFFFFFFu) {
                const int bk = (int)(w >> 21);
                const int pos = atomicAdd(&sm.m.cur[bk], 1);
                if (pos < (bk + 1) * CAP) perm[pos] = w;   // overflow guard
            }
        }
        return;
    }

    // ---------------- gemm: z = h @ W, fused s_l/s_r ----------------
    const int wave = tid >> 6;
    const int lane = tid & 63;
    const int nbase = ((int)blockIdx.x - ms_blocks) * 64;

    // stage A: one float4 load -> packed uint2 -> single ds_write_b64
    for (int i = tid; i < 64 * (IN_DIM / 4); i += 256) {
        const int m  = i >> 6;
        const int k4 = i & 63;
        int node = nbase + m;
        if (node >= n_nodes) node = n_nodes - 1;
        const float4 h4 = *(const float4*)&h[(size_t)node * IN_DIM + k4 * 4];
        uint2 p;
        p.x = f2bf_u(h4.x) | (f2bf_u(h4.y) << 16);
        p.y = f2bf_u(h4.z) | (f2bf_u(h4.w) << 16);
        *(uint2*)&sm.As[m * KPAD + k4 * 4] = p;
    }
    __syncthreads();

    f32x4 acc[4];
#pragma unroll
    for (int t = 0; t < 4; ++t) acc[t] = (f32x4){0.f, 0.f, 0.f, 0.f};

    const int col0 = lane & 15;
    const int quad = lane >> 4;
    const int mrow = wave * 16 + col0;
    const int kq   = quad * 8;

#pragma unroll
    for (int ks = 0; ks < IN_DIM / 32; ++ks) {
        const int kb = ks * 32 + kq;
        const short8 a = *(const short8*)&sm.As[mrow * KPAD + kb];
#pragma unroll
        for (int t = 0; t < 4; ++t) {
            const short8 b = *(const short8*)&Wt[(t * 16 + col0) * IN_DIM + kb];
            acc[t] = __builtin_amdgcn_mfma_f32_16x16x32_bf16(a, b, acc[t], 0, 0, 0);
        }
    }

    float al[4], ar[4];
#pragma unroll
    for (int t = 0; t < 4; ++t) {
        al[t] = a_attn[t * 16 + col0];
        ar[t] = a_attn[OUT_DIM + t * 16 + col0];
    }
#pragma unroll
    for (int r = 0; r < 4; ++r) {
        const int m = nbase + wave * 16 + quad * 4 + r;
        const bool live = m < n_nodes;
        float sl = 0.f, sr = 0.f;
#pragma unroll
        for (int t = 0; t < 4; ++t) {
            const float v = acc[t][r];
            if (live) z_bf[(size_t)m * OUT_DIM + t * 16 + col0] = (ushort_t)f2bf(v);
            sl += v * al[t];
            sr += v * ar[t];
        }
#pragma unroll
        for (int off = 1; off < 16; off <<= 1) {
            sl += __shfl_xor(sl, off, 16);
            sr += __shfl_xor(sr, off, 16);
        }
        if (live && col0 == 0) { s_l[m] = sl; s_r[m] = sr; }
    }
}

// ---------------------------------------------------------------------------
// K2: fused per-bucket CSR + softmax gather (best-measured design: CSR built
// in LDS, register accumulation, x8-unrolled independent gathers for MLP).
// One block (512 thr) per bucket; quarter-wave (16 lanes) per dst.
// ---------------------------------------------------------------------------
__global__ __launch_bounds__(512)
void gather_kernel(const unsigned* __restrict__ perm, const int* __restrict__ cnt,
                   const float* __restrict__ s_l, const float* __restrict__ s_r,
                   const ushort_t* __restrict__ z_bf, float* __restrict__ out,
                   int n_nodes)
{
    __shared__ unsigned eds[CAP];
    __shared__ ushort_t srcs[CAP];
    __shared__ int hist[32], starts[33], cur[32];

    const int tid = threadIdx.x;
    const int b   = blockIdx.x;
    int nE = cnt[b];
    if (nE > CAP) nE = CAP;

    if (tid < 32) hist[tid] = 0;
    __syncthreads();

    for (int i = tid; i < nE; i += 512) {
        const unsigned p = perm[(size_t)b * CAP + i];
        eds[i] = p;
        atomicAdd(&hist[(p >> 16) & 31], 1);
    }
    __syncthreads();

    if (tid < 32) {
        const int v = hist[tid];
        int inc = v;
#pragma unroll
        for (int off = 1; off < 32; off <<= 1) {
            const int u = __shfl_up(inc, off, 32);
            if (tid >= off) inc += u;
        }
        starts[tid + 1] = inc;
        cur[tid] = inc - v;
        if (tid == 0) starts[0] = 0;
    }
    __syncthreads();

    for (int i = tid; i < nE; i += 512) {
        const unsigned p = eds[i];
        const int pos = atomicAdd(&cur[(p >> 16) & 31], 1);
        srcs[pos] = (ushort_t)(p & 0xFFFFu);
    }
    __syncthreads();

    const int ld = tid >> 4;        // 0..31: dst within bucket
    const int c  = tid & 15;        // column quad
    const int d  = b * 32 + ld;
    if (d >= n_nodes) return;

    int k = starts[ld];
    const int ke = starts[ld + 1];
    const float srd = s_r[d];

    float a0 = 0.f, a1 = 0.f, a2 = 0.f, a3 = 0.f, den = 0.f;

    for (; k + 8 <= ke; k += 8) {
        int   s[8];
        float l[8];
        uint2 q[8];
#pragma unroll
        for (int j = 0; j < 8; ++j) s[j] = srcs[k + j];
#pragma unroll
        for (int j = 0; j < 8; ++j) {
            l[j] = s_l[s[j]];
            q[j] = *(const uint2*)&z_bf[(size_t)s[j] * OUT_DIM + c * 4];
        }
#pragma unroll
        for (int j = 0; j < 8; ++j) {
            float e = l[j] + srd;
            e = e > 0.f ? e : NEG_SLOPE * e;
            const float x = __expf(e);
            den += x;
            a0 += x * bf2f(q[j].x & 0xFFFFu);
            a1 += x * bf2f(q[j].x >> 16);
            a2 += x * bf2f(q[j].y & 0xFFFFu);
            a3 += x * bf2f(q[j].y >> 16);
        }
    }
    for (; k + 4 <= ke; k += 4) {
        int   s[4];
        float l[4];
        uint2 q[4];
#pragma unroll
        for (int j = 0; j < 4; ++j) s[j] = srcs[k + j];
#pragma unroll
        for (int j = 0; j < 4; ++j) {
            l[j] = s_l[s[j]];
            q[j] = *(const uint2*)&z_bf[(size_t)s[j] * OUT_DIM + c * 4];
        }
#pragma unroll
        for (int j = 0; j < 4; ++j) {
            float e = l[j] + srd;
            e = e > 0.f ? e : NEG_SLOPE * e;
            const float x = __expf(e);
            den += x;
            a0 += x * bf2f(q[j].x & 0xFFFFu);
            a1 += x * bf2f(q[j].x >> 16);
            a2 += x * bf2f(q[j].y & 0xFFFFu);
            a3 += x * bf2f(q[j].y >> 16);
        }
    }
    for (; k < ke; ++k) {
        const int s0 = srcs[k];
        float e = s_l[s0] + srd;
        e = e > 0.f ? e : NEG_SLOPE * e;
        const float x = __expf(e);
        const uint2 q0 = *(const uint2*)&z_bf[(size_t)s0 * OUT_DIM + c * 4];
        den += x;
        a0 += x * bf2f(q0.x & 0xFFFFu);
        a1 += x * bf2f(q0.x >> 16);
        a2 += x * bf2f(q0.y & 0xFFFFu);
        a3 += x * bf2f(q0.y >> 16);
    }

    const float inv = den > 0.f ? 1.f / den : 0.f;
    float4 o;
    o.x = a0 * inv; o.y = a1 * inv; o.z = a2 * inv; o.w = a3 * inv;
    *(float4*)&out[(size_t)d * OUT_DIM + c * 4] = o;
}

extern "C" void kernel_launch(void* const* d_in, const int* in_sizes, int n_in,
                              void* d_out, int out_size, void* d_ws, size_t ws_size,
                              hipStream_t stream)
{
    const float* h        = (const float*)d_in[0];
    const int*   edge_src = (const int*)  d_in[1];
    const int*   edge_dst = (const int*)  d_in[2];
    const float* W        = (const float*)d_in[3];
    const float* a_attn   = (const float*)d_in[4];
    float*       out      = (float*)d_out;

    const int n_nodes = in_sizes[0] / IN_DIM;   // 50000
    const int n_edges = in_sizes[1];            // 800000
    const int nbuck   = (n_nodes + 31) >> 5;    // 1563

    // ---- workspace layout (16B-aligned regions) ----------------------------
    char* wsb = (char*)d_ws;
    short*    Wt   = (short*)wsb;
    size_t off = (size_t)IN_DIM * OUT_DIM * sizeof(short);          // 32 KB
    ushort_t* z_bf = (ushort_t*)(wsb + off);
    off += (size_t)n_nodes * OUT_DIM * sizeof(ushort_t);            // 6.4 MB
    float*    s_l  = (float*)(wsb + off);  off += (size_t)n_nodes * 4;
    float*    s_r  = (float*)(wsb + off);  off += (size_t)n_nodes * 4;
    int*      cnt  = (int*)(wsb + off);    off += ((size_t)nbuck * 4 + 15) & ~(size_t)15;
    unsigned* perm = (unsigned*)(wsb + off);                        // nbuck*CAP*4 = 6.4 MB

    const int ms_blocks   = (n_edges + EPB - 1) / EPB;   // 196
    const int gemm_blocks = (n_nodes + 63) / 64;         // 782

    prep_kernel<<<8, 256, 0, stream>>>(W, Wt, cnt, nbuck);
    fused_kernel<<<ms_blocks + gemm_blocks, 256, 0, stream>>>(
        h, Wt, a_attn, z_bf, s_l, s_r, edge_src, edge_dst, cnt, perm,
        n_nodes, n_edges, nbuck, ms_blocks);
    gather_kernel<<<nbuck, 512, 0, stream>>>(
        perm, cnt, s_l, s_r, z_bf, out, n_nodes);
}